// Round 5
// baseline (2612.538 us; speedup 1.0000x reference)
//
#include <hip/hip_runtime.h>
#include <cstdint>

// ---------------- problem constants ----------------
#define CDIM 768
#define NHEAD 12
#define HD 64
#define WSZ 14
#define HW 196          // 14*14 tokens per window
#define NWIN 50         // 2 * 5 * 5 windows
#define MWINP 9856      // 50*196=9800 padded to 77*128
#define MTOK 8192       // 2*64*64
#define MLPD 3072

typedef unsigned short u16;
typedef short s16x8 __attribute__((ext_vector_type(8)));
typedef float f32x4 __attribute__((ext_vector_type(4)));

__device__ __forceinline__ float bf2f(u16 u) {
  union { uint32_t i; float f; } v; v.i = ((uint32_t)u) << 16; return v.f;
}
__device__ __forceinline__ u16 f2bf(float f) {
  union { float f; uint32_t i; } v; v.f = f;
  uint32_t u = v.i;
  return (u16)((u + 0x7FFFu + ((u >> 16) & 1u)) >> 16);   // RNE, finite inputs
}

// ---------------- weight transpose + bf16 cast:  W[K,N] -> WT[N,K] ----------------
__global__ __launch_bounds__(256) void k_transpose(const float* __restrict__ W,
                                                   u16* __restrict__ WT, int K, int N) {
  __shared__ float tile[32][33];
  const int tx = threadIdx.x & 31, ty = threadIdx.x >> 5;   // 32 x 8
  const int bn = blockIdx.x * 32, bk = blockIdx.y * 32;
#pragma unroll
  for (int r = 0; r < 4; ++r)
    tile[ty + r * 8][tx] = W[(size_t)(bk + ty + r * 8) * N + bn + tx];
  __syncthreads();
#pragma unroll
  for (int r = 0; r < 4; ++r)
    WT[(size_t)(bn + ty + r * 8) * K + bk + tx] = f2bf(tile[tx][ty + r * 8]);
}

// ---------------- LN1 + window partition (zero pad) -> bf16 [MWINP, 768] ----------------
__global__ __launch_bounds__(256) void k_ln1(const float* __restrict__ x, const float* __restrict__ g,
                                             const float* __restrict__ b, u16* __restrict__ xnwin) {
  const int row = blockIdx.x * 4 + (threadIdx.x >> 6);
  const int lane = threadIdx.x & 63;
  const int win = row / HW, p = row % HW;
  bool valid = win < NWIN;
  int tok = 0;
  if (valid) {
    int bw = win / 25, rem = win % 25;
    int wr = rem / 5, wc = rem % 5;
    int i = p / WSZ, j = p % WSZ;
    int hh = wr * WSZ + i, ww = wc * WSZ + j;
    valid = (hh < 64) && (ww < 64);
    tok = (bw * 64 + hh) * 64 + ww;
  }
  u16* orow = xnwin + (size_t)row * CDIM;
  if (!valid) {
    ushort4 z; z.x = z.y = z.z = z.w = 0;
#pragma unroll
    for (int c = 0; c < 3; ++c) ((ushort4*)orow)[c * 64 + lane] = z;
    return;
  }
  const float4* xr = (const float4*)(x + (size_t)tok * CDIM);
  float4 v[3];
  float s = 0.f, sq = 0.f;
#pragma unroll
  for (int c = 0; c < 3; ++c) {
    v[c] = xr[c * 64 + lane];
    s += v[c].x + v[c].y + v[c].z + v[c].w;
    sq += v[c].x * v[c].x + v[c].y * v[c].y + v[c].z * v[c].z + v[c].w * v[c].w;
  }
#pragma unroll
  for (int off = 32; off > 0; off >>= 1) { s += __shfl_xor(s, off); sq += __shfl_xor(sq, off); }
  const float mean = s * (1.f / CDIM);
  const float rstd = rsqrtf(sq * (1.f / CDIM) - mean * mean + 1e-5f);
#pragma unroll
  for (int c = 0; c < 3; ++c) {
    float4 gv = ((const float4*)g)[c * 64 + lane];
    float4 bv = ((const float4*)b)[c * 64 + lane];
    ushort4 o;
    o.x = f2bf((v[c].x - mean) * rstd * gv.x + bv.x);
    o.y = f2bf((v[c].y - mean) * rstd * gv.y + bv.y);
    o.z = f2bf((v[c].z - mean) * rstd * gv.z + bv.z);
    o.w = f2bf((v[c].w - mean) * rstd * gv.w + bv.w);
    ((ushort4*)orow)[c * 64 + lane] = o;
  }
}

// ---------------- LN2 (plain rows) ----------------
__global__ __launch_bounds__(256) void k_ln2(const float* __restrict__ xin, const float* __restrict__ g,
                                             const float* __restrict__ b, u16* __restrict__ xn2) {
  const int row = blockIdx.x * 4 + (threadIdx.x >> 6);
  const int lane = threadIdx.x & 63;
  const float4* xr = (const float4*)(xin + (size_t)row * CDIM);
  float4 v[3];
  float s = 0.f, sq = 0.f;
#pragma unroll
  for (int c = 0; c < 3; ++c) {
    v[c] = xr[c * 64 + lane];
    s += v[c].x + v[c].y + v[c].z + v[c].w;
    sq += v[c].x * v[c].x + v[c].y * v[c].y + v[c].z * v[c].z + v[c].w * v[c].w;
  }
#pragma unroll
  for (int off = 32; off > 0; off >>= 1) { s += __shfl_xor(s, off); sq += __shfl_xor(sq, off); }
  const float mean = s * (1.f / CDIM);
  const float rstd = rsqrtf(sq * (1.f / CDIM) - mean * mean + 1e-5f);
  u16* orow = xn2 + (size_t)row * CDIM;
#pragma unroll
  for (int c = 0; c < 3; ++c) {
    float4 gv = ((const float4*)g)[c * 64 + lane];
    float4 bv = ((const float4*)b)[c * 64 + lane];
    ushort4 o;
    o.x = f2bf((v[c].x - mean) * rstd * gv.x + bv.x);
    o.y = f2bf((v[c].y - mean) * rstd * gv.y + bv.y);
    o.z = f2bf((v[c].z - mean) * rstd * gv.z + bv.z);
    o.w = f2bf((v[c].w - mean) * rstd * gv.w + bv.w);
    ((ushort4*)orow)[c * 64 + lane] = o;
  }
}

// ---------------- 128x128 MFMA GEMM,  C = A[M,K] * BT[N,K]^T  (bf16 in, f32 acc) ----------------
// EPI: 0 = +bias -> bf16   (QKV)
//      1 = +bias, window-unpartition+crop, += resid(x) -> f32 d_out   (proj)
//      2 = +bias, exact GELU -> bf16   (MLP1)
//      3 = +bias, accumulate into f32 out (+=)   (MLP2 residual)
template <int EPI>
__global__ __launch_bounds__(256) void k_gemm(const u16* __restrict__ A, const u16* __restrict__ BT,
                                              const float* __restrict__ bias, void* __restrict__ outp,
                                              const float* __restrict__ resid, int M, int N, int K) {
  __shared__ __align__(16) char lds[16384];
  char* ldsA = lds;
  char* ldsB = lds + 8192;
  const int t = threadIdx.x;
  const int lane = t & 63, wav = t >> 6;
  const int wm = wav >> 1, wn = wav & 1;
  const int lr = lane & 15, lg = lane >> 4;
  const int m0 = blockIdx.y * 128, n0 = blockIdx.x * 128;
  const int sr = t & 127, sg = t >> 7;

  // LDS layout: slot(g, row) = g*128 + row, 16B per slot (8 bf16 of k-octet g)
  const u16* gA0 = A + (size_t)(m0 + sr) * K + sg * 8;
  const u16* gA1 = gA0 + 16;
  const u16* gB0 = BT + (size_t)(n0 + sr) * K + sg * 8;
  const u16* gB1 = gB0 + 16;
  char* lA0 = ldsA + t * 16;
  char* lA1 = lA0 + 4096;
  char* lB0 = ldsB + t * 16;
  char* lB1 = lB0 + 4096;

  const char* pa = ldsA + (lg * 128 + wm * 64 + lr) * 16;
  const char* pb = ldsB + (lg * 128 + wn * 64 + lr) * 16;

  f32x4 acc[4][4];
#pragma unroll
  for (int i = 0; i < 4; ++i)
#pragma unroll
    for (int j = 0; j < 4; ++j) { acc[i][j][0] = 0.f; acc[i][j][1] = 0.f; acc[i][j][2] = 0.f; acc[i][j][3] = 0.f; }

  uint4 ra0 = *(const uint4*)gA0, ra1 = *(const uint4*)gA1;
  uint4 rb0 = *(const uint4*)gB0, rb1 = *(const uint4*)gB1;

  const int KT = K >> 5;
  for (int kt = 0; kt < KT; ++kt) {
    __syncthreads();
    *(uint4*)lA0 = ra0; *(uint4*)lA1 = ra1;
    *(uint4*)lB0 = rb0; *(uint4*)lB1 = rb1;
    __syncthreads();
    if (kt + 1 < KT) {   // prefetch next tile; overlaps with MFMA below
      gA0 += 32; gA1 += 32; gB0 += 32; gB1 += 32;
      ra0 = *(const uint4*)gA0; ra1 = *(const uint4*)gA1;
      rb0 = *(const uint4*)gB0; rb1 = *(const uint4*)gB1;
    }
    s16x8 av[4], bv[4];
#pragma unroll
    for (int i = 0; i < 4; ++i) av[i] = *(const s16x8*)(pa + i * 256);
#pragma unroll
    for (int j = 0; j < 4; ++j) bv[j] = *(const s16x8*)(pb + j * 256);
#pragma unroll
    for (int i = 0; i < 4; ++i)
#pragma unroll
      for (int j = 0; j < 4; ++j)
        acc[i][j] = __builtin_amdgcn_mfma_f32_16x16x32_bf16(av[i], bv[j], acc[i][j], 0, 0, 0);
  }

#pragma unroll
  for (int i = 0; i < 4; ++i) {
#pragma unroll
    for (int j = 0; j < 4; ++j) {
      const int gcol = n0 + wn * 64 + j * 16 + lr;
      const float bc = bias[gcol];
#pragma unroll
      for (int r = 0; r < 4; ++r) {
        const int grow = m0 + wm * 64 + i * 16 + lg * 4 + r;
        const float cv = acc[i][j][r] + bc;
        if constexpr (EPI == 0) {
          ((u16*)outp)[(size_t)grow * N + gcol] = f2bf(cv);
        } else if constexpr (EPI == 1) {
          const int winI = grow / HW, p = grow % HW;
          if (winI < NWIN) {
            const int bw = winI / 25, rem = winI % 25;
            const int wr = rem / 5, wc = rem % 5;
            const int i2 = p / WSZ, j2 = p % WSZ;
            const int hh = wr * WSZ + i2, ww = wc * WSZ + j2;
            if (hh < 64 && ww < 64) {
              const size_t tok = (size_t)(bw * 64 + hh) * 64 + ww;
              ((float*)outp)[tok * CDIM + gcol] = resid[tok * CDIM + gcol] + cv;
            }
          }
        } else if constexpr (EPI == 2) {
          const float gel = 0.5f * cv * (1.f + erff(cv * 0.70710678118654752f));
          ((u16*)outp)[(size_t)grow * N + gcol] = f2bf(gel);
        } else {
          ((float*)outp)[(size_t)grow * N + gcol] += cv;
        }
      }
    }
  }
}

// ---------------- decomposed rel-pos bias:  biasbuf[wh][p][c] ----------------
// c in [0,14): sum_d q_d * rel_h[(p/14) - c + 13][d]    (key-row part)
// c in [14,28): sum_d q_d * rel_w[(p%14) - (c-14) + 13][d]  (key-col part)
__global__ __launch_bounds__(256) void k_relbias(const u16* __restrict__ qkv, const float* __restrict__ rel_h,
                                                 const float* __restrict__ rel_w, float* __restrict__ biasbuf) {
  const int idx = blockIdx.x * 256 + threadIdx.x;
  if (idx >= NWIN * NHEAD * HW * 28) return;
  const int c = idx % 28;
  const int p = (idx / 28) % HW;
  const int wh = idx / (28 * HW);
  const int win = wh / NHEAD, head = wh % NHEAD;
  const int i = p / WSZ, j = p % WSZ;
  const float* tbl = (c < 14) ? (rel_h + (size_t)(i - c + 13) * HD)
                              : (rel_w + (size_t)(j - (c - 14) + 13) * HD);
  const u16* q = qkv + ((size_t)win * HW + p) * 2304 + head * HD;
  float acc = 0.f;
#pragma unroll 8
  for (int d = 0; d < HD; ++d) acc += bf2f(q[d]) * tbl[d];
  biasbuf[idx] = acc;
}

// ---------------- attention: one block per (window, head), vector math ----------------
__global__ __launch_bounds__(256) void k_attn(const u16* __restrict__ qkv, const float* __restrict__ biasbuf,
                                              u16* __restrict__ attnout) {
  __shared__ u16 Kt[HD][HW];        // K transposed: conflict-free lane=key reads
  __shared__ u16 Vlds[HW][HD];      // row-major: conflict-free lane=d reads
  __shared__ ushort4 plds4[4][HW];  // per-wave probs, 4 q-rows packed bf16
  __shared__ float4 qlds4[4][HD];   // per-wave scaled q, 4 q-rows packed f32
  const int wh = blockIdx.x;
  const int win = wh / NHEAD, head = wh % NHEAD;
  const int t = threadIdx.x, lane = t & 63, w = t >> 6;
  const size_t rowbase = (size_t)win * HW;

  // stage K (transposed) and V
  for (int i = t; i < 2 * HW * 8; i += 256) {
    const int half = i / (HW * 8);
    const int ii = i % (HW * 8);
    const int kr = ii >> 3, c = ii & 7;
    const uint4 v = *(const uint4*)(qkv + (rowbase + kr) * 2304 + (half ? 1536 : 768) + head * HD + c * 8);
    if (half) {
      *(uint4*)&Vlds[kr][c * 8] = v;
    } else {
      const uint32_t vv[4] = {v.x, v.y, v.z, v.w};
#pragma unroll
      for (int e = 0; e < 4; ++e) {
        Kt[c * 8 + 2 * e][kr]     = (u16)(vv[e] & 0xffffu);
        Kt[c * 8 + 2 * e + 1][kr] = (u16)(vv[e] >> 16);
      }
    }
  }
  __syncthreads();

  const float* bbase = biasbuf + (size_t)wh * HW * 28;
  for (int qc = w; qc < 49; qc += 4) {   // 4 q-rows per iteration, per wave
    const int r0 = qc * 4;
    float4 q4;
    q4.x = bf2f(qkv[(rowbase + r0 + 0) * 2304 + head * HD + lane]) * 0.125f;
    q4.y = bf2f(qkv[(rowbase + r0 + 1) * 2304 + head * HD + lane]) * 0.125f;
    q4.z = bf2f(qkv[(rowbase + r0 + 2) * 2304 + head * HD + lane]) * 0.125f;
    q4.w = bf2f(qkv[(rowbase + r0 + 3) * 2304 + head * HD + lane]) * 0.125f;
    qlds4[w][lane] = q4;

    float s[4][4];   // [key-chunk][q-row]
#pragma unroll
    for (int kc = 0; kc < 4; ++kc) {
      const int key = kc * 64 + lane;
      const bool kvalid = key < HW;
      const int kcl = kvalid ? key : 0;
      float a0 = 0.f, a1 = 0.f, a2 = 0.f, a3 = 0.f;
      for (int d = 0; d < HD; ++d) {
        const float4 qv = qlds4[w][d];          // broadcast
        const float kvf = bf2f(Kt[d][kcl]);
        a0 += qv.x * kvf; a1 += qv.y * kvf; a2 += qv.z * kvf; a3 += qv.w * kvf;
      }
      if (kvalid) {
        const int kh = key / WSZ, kw = key % WSZ;
        const float* bb = bbase + (size_t)r0 * 28;
        a0 += bb[kh]          + bb[14 + kw];
        a1 += bb[28 + kh]     + bb[28 + 14 + kw];
        a2 += bb[56 + kh]     + bb[56 + 14 + kw];
        a3 += bb[84 + kh]     + bb[84 + 14 + kw];
      } else {
        a0 = a1 = a2 = a3 = -1e30f;
      }
      s[kc][0] = a0; s[kc][1] = a1; s[kc][2] = a2; s[kc][3] = a3;
    }
    // softmax over 196 keys per row (row spread over 64 lanes x 4 chunks)
    float m[4], inv[4];
#pragma unroll
    for (int rr = 0; rr < 4; ++rr) {
      float mm = fmaxf(fmaxf(s[0][rr], s[1][rr]), fmaxf(s[2][rr], s[3][rr]));
#pragma unroll
      for (int off = 32; off > 0; off >>= 1) mm = fmaxf(mm, __shfl_xor(mm, off));
      m[rr] = mm;
    }
#pragma unroll
    for (int kc = 0; kc < 4; ++kc)
#pragma unroll
      for (int rr = 0; rr < 4; ++rr) s[kc][rr] = expf(s[kc][rr] - m[rr]);
#pragma unroll
    for (int rr = 0; rr < 4; ++rr) {
      float sum = s[0][rr] + s[1][rr] + s[2][rr] + s[3][rr];
#pragma unroll
      for (int off = 32; off > 0; off >>= 1) sum += __shfl_xor(sum, off);
      inv[rr] = 1.f / sum;
    }
#pragma unroll
    for (int kc = 0; kc < 4; ++kc) {
      const int key = kc * 64 + lane;
      if (key < HW) {
        ushort4 o;
        o.x = f2bf(s[kc][0] * inv[0]);
        o.y = f2bf(s[kc][1] * inv[1]);
        o.z = f2bf(s[kc][2] * inv[2]);
        o.w = f2bf(s[kc][3] * inv[3]);
        plds4[w][key] = o;
      }
    }
    // PV: lane = output dim d
    float o0 = 0.f, o1 = 0.f, o2 = 0.f, o3 = 0.f;
    for (int k = 0; k < HW; ++k) {
      const ushort4 pq = plds4[w][k];           // broadcast
      const float vf = bf2f(Vlds[k][lane]);
      o0 += bf2f(pq.x) * vf;
      o1 += bf2f(pq.y) * vf;
      o2 += bf2f(pq.z) * vf;
      o3 += bf2f(pq.w) * vf;
    }
    u16* orow = attnout + (rowbase + r0) * (size_t)CDIM + head * HD + lane;
    orow[0]        = f2bf(o0);
    orow[CDIM]     = f2bf(o1);
    orow[2 * CDIM] = f2bf(o2);
    orow[3 * CDIM] = f2bf(o3);
  }
}

// ---------------- host launcher ----------------
extern "C" void kernel_launch(void* const* d_in, const int* in_sizes, int n_in,
                              void* d_out, int out_size, void* d_ws, size_t ws_size,
                              hipStream_t stream) {
  const float* x     = (const float*)d_in[0];
  const float* g1    = (const float*)d_in[1];
  const float* b1    = (const float*)d_in[2];
  const float* w_qkv = (const float*)d_in[3];
  const float* b_qkv = (const float*)d_in[4];
  const float* w_proj= (const float*)d_in[5];
  const float* b_proj= (const float*)d_in[6];
  const float* rel_h = (const float*)d_in[7];
  const float* rel_w = (const float*)d_in[8];
  const float* g2    = (const float*)d_in[9];
  const float* b2    = (const float*)d_in[10];
  const float* w1    = (const float*)d_in[11];
  const float* b1m   = (const float*)d_in[12];
  const float* w2    = (const float*)d_in[13];
  const float* b2m   = (const float*)d_in[14];
  float* out = (float*)d_out;
  char* ws = (char*)d_ws;

  // workspace layout (bytes, 256-aligned); total 107,936,256
  u16* wqkvT   = (u16*)(ws + 0);          // [2304][768]   3,538,944
  u16* wprojT  = (u16*)(ws + 3538944);    // [768][768]    1,179,648
  u16* w1T     = (u16*)(ws + 4718592);    // [3072][768]   4,718,592
  u16* w2T     = (u16*)(ws + 9437184);    // [768][3072]   4,718,592
  u16* xnwin   = (u16*)(ws + 14155776);   // [9856][768]  15,138,816  (reused as xn2)
  u16* qkv     = (u16*)(ws + 29294592);   // [9856][2304] 50,331,648  (reused as mlp hidden h)
  u16* attnout = (u16*)(ws + 79626240);   // [9856][768]  15,138,816
  float* biasbuf = (float*)(ws + 94765056); // [600][196][28] 13,171,200

  k_transpose<<<dim3(2304 / 32, 768 / 32), 256, 0, stream>>>(w_qkv, wqkvT, 768, 2304);
  k_transpose<<<dim3(768 / 32, 768 / 32), 256, 0, stream>>>(w_proj, wprojT, 768, 768);
  k_transpose<<<dim3(3072 / 32, 768 / 32), 256, 0, stream>>>(w1, w1T, 768, 3072);
  k_transpose<<<dim3(768 / 32, 3072 / 32), 256, 0, stream>>>(w2, w2T, 3072, 768);

  k_ln1<<<MWINP / 4, 256, 0, stream>>>(x, g1, b1, xnwin);

  k_gemm<0><<<dim3(2304 / 128, MWINP / 128), 256, 0, stream>>>(xnwin, wqkvT, b_qkv, qkv, nullptr, MWINP, 2304, 768);

  k_relbias<<<(NWIN * NHEAD * HW * 28 + 255) / 256, 256, 0, stream>>>(qkv, rel_h, rel_w, biasbuf);

  k_attn<<<NWIN * NHEAD, 256, 0, stream>>>(qkv, biasbuf, attnout);

  k_gemm<1><<<dim3(768 / 128, MWINP / 128), 256, 0, stream>>>(attnout, wprojT, b_proj, out, x, MWINP, 768, 768);

  k_ln2<<<MTOK / 4, 256, 0, stream>>>(out, g2, b2, xnwin /* xn2 */);

  k_gemm<2><<<dim3(3072 / 128, MTOK / 128), 256, 0, stream>>>(xnwin, w1T, b1m, qkv /* h */, nullptr, MTOK, 3072, 768);

  k_gemm<3><<<dim3(768 / 128, MTOK / 128), 256, 0, stream>>>(qkv /* h */, w2T, b2m, out, nullptr, MTOK, 768, 3072);
}

// Round 6
// 659.598 us; speedup vs baseline: 3.9608x; 3.9608x over previous
//
#include <hip/hip_runtime.h>
#include <cstdint>

// ---------------- problem constants ----------------
#define CDIM 768
#define NHEAD 12
#define HD 64
#define WSZ 14
#define HW 196          // 14*14 tokens per window
#define NWIN 50         // 2 * 5 * 5 windows
#define MWINP 9856      // 50*196=9800 padded to 77*128
#define MTOK 8192       // 2*64*64
#define MLPD 3072

typedef unsigned short u16;
typedef short s16x8 __attribute__((ext_vector_type(8)));
typedef float f32x4 __attribute__((ext_vector_type(4)));

__device__ __forceinline__ float bf2f(u16 u) {
  union { uint32_t i; float f; } v; v.i = ((uint32_t)u) << 16; return v.f;
}
__device__ __forceinline__ u16 f2bf(float f) {
  union { float f; uint32_t i; } v; v.f = f;
  uint32_t u = v.i;
  return (u16)((u + 0x7FFFu + ((u >> 16) & 1u)) >> 16);   // RNE, finite inputs
}

// ---------------- weight transpose + bf16 cast:  W[K,N] -> WT[N,K] ----------------
__global__ __launch_bounds__(256) void k_transpose(const float* __restrict__ W,
                                                   u16* __restrict__ WT, int K, int N) {
  __shared__ float tile[32][33];
  const int tx = threadIdx.x & 31, ty = threadIdx.x >> 5;   // 32 x 8
  const int bn = blockIdx.x * 32, bk = blockIdx.y * 32;
#pragma unroll
  for (int r = 0; r < 4; ++r)
    tile[ty + r * 8][tx] = W[(size_t)(bk + ty + r * 8) * N + bn + tx];
  __syncthreads();
#pragma unroll
  for (int r = 0; r < 4; ++r)
    WT[(size_t)(bn + ty + r * 8) * K + bk + tx] = f2bf(tile[tx][ty + r * 8]);
}

// ---------------- LN1 + window partition (zero pad) -> bf16 [MWINP, 768] ----------------
__global__ __launch_bounds__(256) void k_ln1(const float* __restrict__ x, const float* __restrict__ g,
                                             const float* __restrict__ b, u16* __restrict__ xnwin) {
  const int row = blockIdx.x * 4 + (threadIdx.x >> 6);
  const int lane = threadIdx.x & 63;
  const int win = row / HW, p = row % HW;
  bool valid = win < NWIN;
  int tok = 0;
  if (valid) {
    int bw = win / 25, rem = win % 25;
    int wr = rem / 5, wc = rem % 5;
    int i = p / WSZ, j = p % WSZ;
    int hh = wr * WSZ + i, ww = wc * WSZ + j;
    valid = (hh < 64) && (ww < 64);
    tok = (bw * 64 + hh) * 64 + ww;
  }
  u16* orow = xnwin + (size_t)row * CDIM;
  if (!valid) {
    ushort4 z; z.x = z.y = z.z = z.w = 0;
#pragma unroll
    for (int c = 0; c < 3; ++c) ((ushort4*)orow)[c * 64 + lane] = z;
    return;
  }
  const float4* xr = (const float4*)(x + (size_t)tok * CDIM);
  float4 v[3];
  float s = 0.f, sq = 0.f;
#pragma unroll
  for (int c = 0; c < 3; ++c) {
    v[c] = xr[c * 64 + lane];
    s += v[c].x + v[c].y + v[c].z + v[c].w;
    sq += v[c].x * v[c].x + v[c].y * v[c].y + v[c].z * v[c].z + v[c].w * v[c].w;
  }
#pragma unroll
  for (int off = 32; off > 0; off >>= 1) { s += __shfl_xor(s, off); sq += __shfl_xor(sq, off); }
  const float mean = s * (1.f / CDIM);
  const float rstd = rsqrtf(sq * (1.f / CDIM) - mean * mean + 1e-5f);
#pragma unroll
  for (int c = 0; c < 3; ++c) {
    float4 gv = ((const float4*)g)[c * 64 + lane];
    float4 bv = ((const float4*)b)[c * 64 + lane];
    ushort4 o;
    o.x = f2bf((v[c].x - mean) * rstd * gv.x + bv.x);
    o.y = f2bf((v[c].y - mean) * rstd * gv.y + bv.y);
    o.z = f2bf((v[c].z - mean) * rstd * gv.z + bv.z);
    o.w = f2bf((v[c].w - mean) * rstd * gv.w + bv.w);
    ((ushort4*)orow)[c * 64 + lane] = o;
  }
}

// ---------------- LN2 (plain rows) ----------------
__global__ __launch_bounds__(256) void k_ln2(const float* __restrict__ xin, const float* __restrict__ g,
                                             const float* __restrict__ b, u16* __restrict__ xn2) {
  const int row = blockIdx.x * 4 + (threadIdx.x >> 6);
  const int lane = threadIdx.x & 63;
  const float4* xr = (const float4*)(xin + (size_t)row * CDIM);
  float4 v[3];
  float s = 0.f, sq = 0.f;
#pragma unroll
  for (int c = 0; c < 3; ++c) {
    v[c] = xr[c * 64 + lane];
    s += v[c].x + v[c].y + v[c].z + v[c].w;
    sq += v[c].x * v[c].x + v[c].y * v[c].y + v[c].z * v[c].z + v[c].w * v[c].w;
  }
#pragma unroll
  for (int off = 32; off > 0; off >>= 1) { s += __shfl_xor(s, off); sq += __shfl_xor(sq, off); }
  const float mean = s * (1.f / CDIM);
  const float rstd = rsqrtf(sq * (1.f / CDIM) - mean * mean + 1e-5f);
  u16* orow = xn2 + (size_t)row * CDIM;
#pragma unroll
  for (int c = 0; c < 3; ++c) {
    float4 gv = ((const float4*)g)[c * 64 + lane];
    float4 bv = ((const float4*)b)[c * 64 + lane];
    ushort4 o;
    o.x = f2bf((v[c].x - mean) * rstd * gv.x + bv.x);
    o.y = f2bf((v[c].y - mean) * rstd * gv.y + bv.y);
    o.z = f2bf((v[c].z - mean) * rstd * gv.z + bv.z);
    o.w = f2bf((v[c].w - mean) * rstd * gv.w + bv.w);
    ((ushort4*)orow)[c * 64 + lane] = o;
  }
}

// ---------------- 128x128 MFMA GEMM,  C = A[M,K] * BT[N,K]^T  (bf16 in, f32 acc) ----------------
// EPI: 0 = +bias -> bf16   (QKV)
//      1 = +bias, window-unpartition+crop, += resid(x) -> f32 d_out   (proj)
//      2 = +bias, exact GELU -> bf16   (MLP1)
//      3 = +bias, accumulate into f32 out (+=)   (MLP2 residual)
template <int EPI>
__global__ __launch_bounds__(256) void k_gemm(const u16* __restrict__ A, const u16* __restrict__ BT,
                                              const float* __restrict__ bias, void* __restrict__ outp,
                                              const float* __restrict__ resid, int M, int N, int K) {
  __shared__ __align__(16) char lds[16384];
  char* ldsA = lds;
  char* ldsB = lds + 8192;
  const int t = threadIdx.x;
  const int lane = t & 63, wav = t >> 6;
  const int wm = wav >> 1, wn = wav & 1;
  const int lr = lane & 15, lg = lane >> 4;
  const int m0 = blockIdx.y * 128, n0 = blockIdx.x * 128;
  const int sr = t & 127, sg = t >> 7;

  // LDS layout: slot(g, row) = g*128 + row, 16B per slot (8 bf16 of k-octet g)
  const u16* gA0 = A + (size_t)(m0 + sr) * K + sg * 8;
  const u16* gA1 = gA0 + 16;
  const u16* gB0 = BT + (size_t)(n0 + sr) * K + sg * 8;
  const u16* gB1 = gB0 + 16;
  char* lA0 = ldsA + t * 16;
  char* lA1 = lA0 + 4096;
  char* lB0 = ldsB + t * 16;
  char* lB1 = lB0 + 4096;

  const char* pa = ldsA + (lg * 128 + wm * 64 + lr) * 16;
  const char* pb = ldsB + (lg * 128 + wn * 64 + lr) * 16;

  f32x4 acc[4][4];
#pragma unroll
  for (int i = 0; i < 4; ++i)
#pragma unroll
    for (int j = 0; j < 4; ++j) { acc[i][j][0] = 0.f; acc[i][j][1] = 0.f; acc[i][j][2] = 0.f; acc[i][j][3] = 0.f; }

  uint4 ra0 = *(const uint4*)gA0, ra1 = *(const uint4*)gA1;
  uint4 rb0 = *(const uint4*)gB0, rb1 = *(const uint4*)gB1;

  const int KT = K >> 5;
  for (int kt = 0; kt < KT; ++kt) {
    __syncthreads();
    *(uint4*)lA0 = ra0; *(uint4*)lA1 = ra1;
    *(uint4*)lB0 = rb0; *(uint4*)lB1 = rb1;
    __syncthreads();
    if (kt + 1 < KT) {   // prefetch next tile; overlaps with MFMA below
      gA0 += 32; gA1 += 32; gB0 += 32; gB1 += 32;
      ra0 = *(const uint4*)gA0; ra1 = *(const uint4*)gA1;
      rb0 = *(const uint4*)gB0; rb1 = *(const uint4*)gB1;
    }
    s16x8 av[4], bv[4];
#pragma unroll
    for (int i = 0; i < 4; ++i) av[i] = *(const s16x8*)(pa + i * 256);
#pragma unroll
    for (int j = 0; j < 4; ++j) bv[j] = *(const s16x8*)(pb + j * 256);
#pragma unroll
    for (int i = 0; i < 4; ++i)
#pragma unroll
      for (int j = 0; j < 4; ++j)
        acc[i][j] = __builtin_amdgcn_mfma_f32_16x16x32_bf16(av[i], bv[j], acc[i][j], 0, 0, 0);
  }

#pragma unroll
  for (int i = 0; i < 4; ++i) {
#pragma unroll
    for (int j = 0; j < 4; ++j) {
      const int gcol = n0 + wn * 64 + j * 16 + lr;
      const float bc = bias[gcol];
#pragma unroll
      for (int r = 0; r < 4; ++r) {
        const int grow = m0 + wm * 64 + i * 16 + lg * 4 + r;
        const float cv = acc[i][j][r] + bc;
        if constexpr (EPI == 0) {
          ((u16*)outp)[(size_t)grow * N + gcol] = f2bf(cv);
        } else if constexpr (EPI == 1) {
          const int winI = grow / HW, p = grow % HW;
          if (winI < NWIN) {
            const int bw = winI / 25, rem = winI % 25;
            const int wr = rem / 5, wc = rem % 5;
            const int i2 = p / WSZ, j2 = p % WSZ;
            const int hh = wr * WSZ + i2, ww = wc * WSZ + j2;
            if (hh < 64 && ww < 64) {
              const size_t tok = (size_t)(bw * 64 + hh) * 64 + ww;
              ((float*)outp)[tok * CDIM + gcol] = resid[tok * CDIM + gcol] + cv;
            }
          }
        } else if constexpr (EPI == 2) {
          const float gel = 0.5f * cv * (1.f + erff(cv * 0.70710678118654752f));
          ((u16*)outp)[(size_t)grow * N + gcol] = f2bf(gel);
        } else {
          ((float*)outp)[(size_t)grow * N + gcol] += cv;
        }
      }
    }
  }
}

// ---------------- decomposed rel-pos bias:  biasbuf[wh][p][c] ----------------
// c in [0,14): sum_d q_d * rel_h[(p/14) - c + 13][d]    (key-row part)
// c in [14,28): sum_d q_d * rel_w[(p%14) - (c-14) + 13][d]  (key-col part)
__global__ __launch_bounds__(256) void k_relbias(const u16* __restrict__ qkv, const float* __restrict__ rel_h,
                                                 const float* __restrict__ rel_w, float* __restrict__ biasbuf) {
  const int idx = blockIdx.x * 256 + threadIdx.x;
  if (idx >= NWIN * NHEAD * HW * 28) return;
  const int c = idx % 28;
  const int p = (idx / 28) % HW;
  const int wh = idx / (28 * HW);
  const int win = wh / NHEAD, head = wh % NHEAD;
  const int i = p / WSZ, j = p % WSZ;
  const float* tbl = (c < 14) ? (rel_h + (size_t)(i - c + 13) * HD)
                              : (rel_w + (size_t)(j - (c - 14) + 13) * HD);
  const u16* q = qkv + ((size_t)win * HW + p) * 2304 + head * HD;
  float acc = 0.f;
#pragma unroll 8
  for (int d = 0; d < HD; ++d) acc += bf2f(q[d]) * tbl[d];
  biasbuf[idx] = acc;
}

// ---------------- MFMA attention: one block per (window, head), 4 waves ----------------
// LDS: Kl [208 keys][64 d] bf16, 128B rows, 16B-chunk XOR swizzle (chunk ^ (key&7))
//      Vt [64 d][256 keys] bf16 (cols 0..223 valid, >=196 zeroed), 512B rows,
//         chunk cc: byte = row*512 + (cc>>3)*128 + (((cc&7)^(row&7))<<4)
//      Pb: per-wave [16 q][256 keys] bf16, same chunk mapping as Vt
//      Bl: [196][28] f32 bias slice for this (win,head)
__global__ __launch_bounds__(256) void k_attn(const u16* __restrict__ qkv, const float* __restrict__ biasbuf,
                                              u16* __restrict__ attnout) {
  __shared__ __align__(16) char lds[114112];
  char* Kl = lds;                      // 26624 B
  char* Vt = lds + 26624;              // 32768 B
  char* Pb = lds + 59392;              // 32768 B (4 x 8192)
  float* Bl = (float*)(lds + 92160);   // 21952 B

  const int wh = blockIdx.x;
  const int win = wh / NHEAD, head = wh % NHEAD;
  const int t = threadIdx.x, lane = t & 63, w = t >> 6;
  const int lr = lane & 15, lg = lane >> 4;
  const size_t rowbase = (size_t)win * HW;
  const u16* qbase = qkv + rowbase * 2304 + head * HD;

  // ---- stage K [0..207][64], zero pad keys >= 196 ----
  for (int i = t; i < 208 * 8; i += 256) {
    const int key = i >> 3, c = i & 7;
    uint4 v; v.x = v.y = v.z = v.w = 0u;
    if (key < HW) v = *(const uint4*)(qbase + (size_t)key * 2304 + 768 + c * 8);
    *(uint4*)(Kl + key * 128 + ((c ^ (key & 7)) << 4)) = v;
  }
  // ---- stage V transposed: Vt[d][key], keys 0..223, zero pad >= 196 ----
  for (int i = t; i < 224 * 8; i += 256) {
    const int key = i >> 3, c8 = i & 7;
    uint4 v; v.x = v.y = v.z = v.w = 0u;
    if (key < HW) v = *(const uint4*)(qbase + (size_t)key * 2304 + 1536 + c8 * 8);
    const uint32_t vv[4] = {v.x, v.y, v.z, v.w};
    const int cc = key >> 3, grp = (cc >> 3) << 7, sub = cc & 7, ko = (key & 7) * 2;
#pragma unroll
    for (int e = 0; e < 4; ++e) {
      const int d0 = c8 * 8 + 2 * e;
      *(u16*)(Vt + d0 * 512 + grp + ((sub ^ (d0 & 7)) << 4) + ko) = (u16)(vv[e] & 0xffffu);
      const int d1 = d0 + 1;
      *(u16*)(Vt + d1 * 512 + grp + ((sub ^ (d1 & 7)) << 4) + ko) = (u16)(vv[e] >> 16);
    }
  }
  // ---- stage bias slice [196][28] f32 ----
  {
    const float* bsrc = biasbuf + (size_t)wh * (HW * 28);
    for (int i = t; i < HW * 28; i += 256) Bl[i] = bsrc[i];
  }
  // ---- zero this wave's P cols 208..255 (PV pad; only 208..223 ever read) ----
  {
    char* P = Pb + w * 8192;
    for (int i = lane; i < 16 * 6; i += 64) {
      const int row = i / 6, cc = 26 + i % 6;
      uint4 z; z.x = z.y = z.z = z.w = 0u;
      *(uint4*)(P + row * 512 + ((cc >> 3) << 7) + (((cc & 7) ^ (row & 7)) << 4)) = z;
    }
  }
  __syncthreads();

  char* P = Pb + w * 8192;
  for (int qt = w; qt < 13; qt += 4) {
    const int q0 = qt * 16;
    // Q A-frags: 2 x 32-d chunks, 16B contiguous per lane from global (L2-warm)
    const s16x8 qa0 = *(const s16x8*)(qbase + (size_t)(q0 + lr) * 2304 + lg * 8);
    const s16x8 qa1 = *(const s16x8*)(qbase + (size_t)(q0 + lr) * 2304 + 32 + lg * 8);

    // ---- S = Q K^T over 13 key tiles ----
    f32x4 st[13];
#pragma unroll
    for (int kt = 0; kt < 13; ++kt) {
      const int key = kt * 16 + lr;
      const s16x8 kb0 = *(const s16x8*)(Kl + key * 128 + ((lg ^ (key & 7)) << 4));
      const s16x8 kb1 = *(const s16x8*)(Kl + key * 128 + (((4 + lg) ^ (key & 7)) << 4));
      f32x4 z; z[0] = 0.f; z[1] = 0.f; z[2] = 0.f; z[3] = 0.f;
      z = __builtin_amdgcn_mfma_f32_16x16x32_bf16(qa0, kb0, z, 0, 0, 0);
      z = __builtin_amdgcn_mfma_f32_16x16x32_bf16(qa1, kb1, z, 0, 0, 0);
      st[kt] = z;
    }

    // ---- scale + rel-pos bias + key mask; row max ----
    float mx[4] = {-1e30f, -1e30f, -1e30f, -1e30f};
#pragma unroll
    for (int r = 0; r < 4; ++r) {
      const int q = q0 + 4 * lg + r;
      const float* bq = Bl + (q < HW ? q : HW - 1) * 28;
#pragma unroll
      for (int kt = 0; kt < 13; ++kt) {
        float v;
        if (kt == 12 && lr >= 4) {
          v = -1e30f;                       // keys 196..207 invalid
        } else {
          const int key = kt * 16 + lr;
          const int kh = key / 14, kw = key - kh * 14;
          v = st[kt][r] * 0.125f + bq[kh] + bq[14 + kw];
        }
        st[kt][r] = v;
        mx[r] = fmaxf(mx[r], v);
      }
    }
#pragma unroll
    for (int r = 0; r < 4; ++r)
#pragma unroll
      for (int off = 1; off < 16; off <<= 1) mx[r] = fmaxf(mx[r], __shfl_xor(mx[r], off));

    // ---- exp + row sum ----
    float sum[4] = {0.f, 0.f, 0.f, 0.f};
#pragma unroll
    for (int kt = 0; kt < 13; ++kt)
#pragma unroll
      for (int r = 0; r < 4; ++r) {
        const float e = __expf(st[kt][r] - mx[r]);
        st[kt][r] = e;
        sum[r] += e;
      }
    float inv[4];
#pragma unroll
    for (int r = 0; r < 4; ++r) {
#pragma unroll
      for (int off = 1; off < 16; off <<= 1) sum[r] += __shfl_xor(sum[r], off);
      inv[r] = 1.f / sum[r];
    }

    // ---- write P (bf16, swizzled) ----
#pragma unroll
    for (int r = 0; r < 4; ++r) {
      const int row = 4 * lg + r;
#pragma unroll
      for (int kt = 0; kt < 13; ++kt) {
        const int col = kt * 16 + lr;
        const int cc = col >> 3;
        *(u16*)(P + row * 512 + ((cc >> 3) << 7) + (((cc & 7) ^ (row & 7)) << 4) + (col & 7) * 2)
            = f2bf(st[kt][r] * inv[r]);
      }
    }

    // ---- O = P V over 7 key-blocks of 32, 4 d-tiles ----
#pragma unroll
    for (int dt = 0; dt < 4; ++dt) {
      const int drow = dt * 16 + lr;
      f32x4 oz; oz[0] = 0.f; oz[1] = 0.f; oz[2] = 0.f; oz[3] = 0.f;
#pragma unroll
      for (int kb = 0; kb < 7; ++kb) {
        const int c = kb * 4 + lg;
        const int go = (c >> 3) << 7, sb = c & 7;
        const s16x8 pa = *(const s16x8*)(P + lr * 512 + go + ((sb ^ (lr & 7)) << 4));
        const s16x8 vb = *(const s16x8*)(Vt + drow * 512 + go + ((sb ^ (drow & 7)) << 4));
        oz = __builtin_amdgcn_mfma_f32_16x16x32_bf16(pa, vb, oz, 0, 0, 0);
      }
#pragma unroll
      for (int r = 0; r < 4; ++r) {
        const int q = q0 + 4 * lg + r;
        if (q < HW)
          attnout[(rowbase + q) * (size_t)CDIM + head * HD + drow] = f2bf(oz[r]);
      }
    }
  }
}

// ---------------- host launcher ----------------
extern "C" void kernel_launch(void* const* d_in, const int* in_sizes, int n_in,
                              void* d_out, int out_size, void* d_ws, size_t ws_size,
                              hipStream_t stream) {
  const float* x     = (const float*)d_in[0];
  const float* g1    = (const float*)d_in[1];
  const float* b1    = (const float*)d_in[2];
  const float* w_qkv = (const float*)d_in[3];
  const float* b_qkv = (const float*)d_in[4];
  const float* w_proj= (const float*)d_in[5];
  const float* b_proj= (const float*)d_in[6];
  const float* rel_h = (const float*)d_in[7];
  const float* rel_w = (const float*)d_in[8];
  const float* g2    = (const float*)d_in[9];
  const float* b2    = (const float*)d_in[10];
  const float* w1    = (const float*)d_in[11];
  const float* b1m   = (const float*)d_in[12];
  const float* w2    = (const float*)d_in[13];
  const float* b2m   = (const float*)d_in[14];
  float* out = (float*)d_out;
  char* ws = (char*)d_ws;

  // workspace layout (bytes, 256-aligned); total 107,936,256
  u16* wqkvT   = (u16*)(ws + 0);          // [2304][768]   3,538,944
  u16* wprojT  = (u16*)(ws + 3538944);    // [768][768]    1,179,648
  u16* w1T     = (u16*)(ws + 4718592);    // [3072][768]   4,718,592
  u16* w2T     = (u16*)(ws + 9437184);    // [768][3072]   4,718,592
  u16* xnwin   = (u16*)(ws + 14155776);   // [9856][768]  15,138,816  (reused as xn2)
  u16* qkv     = (u16*)(ws + 29294592);   // [9856][2304] 50,331,648  (reused as mlp hidden h)
  u16* attnout = (u16*)(ws + 79626240);   // [9856][768]  15,138,816
  float* biasbuf = (float*)(ws + 94765056); // [600][196][28] 13,171,200

  k_transpose<<<dim3(2304 / 32, 768 / 32), 256, 0, stream>>>(w_qkv, wqkvT, 768, 2304);
  k_transpose<<<dim3(768 / 32, 768 / 32), 256, 0, stream>>>(w_proj, wprojT, 768, 768);
  k_transpose<<<dim3(3072 / 32, 768 / 32), 256, 0, stream>>>(w1, w1T, 768, 3072);
  k_transpose<<<dim3(768 / 32, 3072 / 32), 256, 0, stream>>>(w2, w2T, 3072, 768);

  k_ln1<<<MWINP / 4, 256, 0, stream>>>(x, g1, b1, xnwin);

  k_gemm<0><<<dim3(2304 / 128, MWINP / 128), 256, 0, stream>>>(xnwin, wqkvT, b_qkv, qkv, nullptr, MWINP, 2304, 768);

  k_relbias<<<(NWIN * NHEAD * HW * 28 + 255) / 256, 256, 0, stream>>>(qkv, rel_h, rel_w, biasbuf);

  k_attn<<<NWIN * NHEAD, 256, 0, stream>>>(qkv, biasbuf, attnout);

  k_gemm<1><<<dim3(768 / 128, MWINP / 128), 256, 0, stream>>>(attnout, wprojT, b_proj, out, x, MWINP, 768, 768);

  k_ln2<<<MTOK / 4, 256, 0, stream>>>(out, g2, b2, xnwin /* xn2 */);

  k_gemm<2><<<dim3(3072 / 128, MTOK / 128), 256, 0, stream>>>(xnwin, w1T, b1m, qkv /* h */, nullptr, MTOK, 3072, 768);

  k_gemm<3><<<dim3(768 / 128, MTOK / 128), 256, 0, stream>>>(qkv /* h */, w2T, b2m, out, nullptr, MTOK, 768, 3072);
}